// Round 6
// baseline (149.314 us; speedup 1.0000x reference)
//
#include <hip/hip_runtime.h>
#include <math.h>
#include <stdint.h>

#define BATCH 4
#define CH    256
#define HH    80
#define WW    80
#define HW    (HH*WW)        // 6400
#define NPIX  (BATCH*HW)     // 25600
#define KK    9
#define CO    18             // 2*K*K offset channels
#define NCHUNK 72            // 9 taps * 8 groups of 32 channels
#define NIV   36             // K=64 intervals (2 chunks each)
#define PXB   32             // pixels per block
#define NBLK  (NPIX/PXB)     // 800 blocks
#define AST   72             // A LDS row stride in halves (144 B, 2-way-free)

typedef _Float16 half8 __attribute__((ext_vector_type(8)));
typedef _Float16 half4 __attribute__((ext_vector_type(4)));
typedef float    f32x4 __attribute__((ext_vector_type(4)));

// ---------------- x NCHW f32 -> xt NHWC f16 ----------------
__global__ __launch_bounds__(256) void k_transpose_x(const float* __restrict__ x,
                                                     _Float16* __restrict__ xt) {
    __shared__ float tile[32][33];
    int b  = blockIdx.z;
    int c0 = blockIdx.y * 32;
    int p0 = blockIdx.x * 32;
    int tx = threadIdx.x;   // 0..31
    int ty = threadIdx.y;   // 0..7
    const float* xb = x + (size_t)b * CH * HW;
    #pragma unroll
    for (int i = 0; i < 32; i += 8)
        tile[ty + i][tx] = xb[(size_t)(c0 + ty + i) * HW + p0 + tx];
    __syncthreads();
    _Float16* xtb = xt + (size_t)b * HW * CH;
    #pragma unroll
    for (int i = 0; i < 32; i += 8)
        xtb[(size_t)(p0 + ty + i) * CH + c0 + tx] = (_Float16)tile[tx][ty + i];
}

// -------- dcn_w [o][c][tap] f32 -> wpk3 [NIV][4 ocq][2 kh][4 nn][64 lane][8] f16 --------
// lane-exact B-fragment order: bf[nn] for wave(ocq,kh) at interval iv is one
// contiguous 1 KB block read at (frag*512 + lane*8).
__global__ __launch_bounds__(256) void k_pack_w3(const float* __restrict__ w,
                                                 _Float16* __restrict__ wp) {
    int idx = blockIdx.x * 256 + threadIdx.x;
    if (idx >= NIV * 4 * 2 * 4 * 64 * 8) return;
    int e    = idx & 7;
    int lane = (idx >> 3) & 63;
    int nn   = (idx >> 9) & 3;
    int kh   = (idx >> 11) & 1;
    int ocq  = (idx >> 12) & 3;
    int iv   = idx >> 14;
    int oc = ocq * 64 + nn * 16 + (lane & 15);
    int kl = kh * 32 + (lane >> 4) * 8 + e;
    int kg = iv * 64 + kl;                 // global K index
    int q  = kg >> 5;                      // chunk
    int tap = q >> 3;
    int c   = (q & 7) * 32 + (kg & 31);
    wp[idx] = (_Float16)w[((size_t)oc * CH + c) * KK + tap];
}

// ---------------- offset_w [18][256][9] f32 -> wop [72 chunk][32 oc][32 k] f16 ----------------
__global__ __launch_bounds__(256) void k_pack_ow(const float* __restrict__ ow,
                                                 _Float16* __restrict__ wop) {
    int idx = blockIdx.x * 256 + threadIdx.x;
    if (idx >= NCHUNK * 32 * 32) return;
    int kq = idx & 31;
    int oc = (idx >> 5) & 31;
    int q  = idx >> 10;
    int tap = q >> 3;
    int c   = (q & 7) * 32 + kq;
    float v = (oc < CO) ? ow[((size_t)oc * CH + c) * KK + tap] : 0.f;
    wop[idx] = (_Float16)v;
}

// ---------------- fused offset-conv + deform-gather + MFMA GEMM + BN/SiLU/residual ----------------
// 512 thr = 8 waves; block = 32 px x 256 oc; wave(ocq=wvi&3, kh=wvi>>2) = 32px x 64oc x k-half
__global__ __launch_bounds__(512) void k_main(const float* __restrict__ x,
                                              const _Float16* __restrict__ xt,
                                              const _Float16* __restrict__ wpk3,
                                              const _Float16* __restrict__ wop,
                                              const float* __restrict__ obias,
                                              const float* __restrict__ gamma,
                                              const float* __restrict__ beta,
                                              const float* __restrict__ mean,
                                              const float* __restrict__ var,
                                              float* __restrict__ out) {
    __shared__ __align__(16) char pool[34816];
    int*      cbase = (int*)pool;                 // [32][9][4] int    4608 B
    float*    cwt   = (float*)(pool + 4608);      // [32][9][4] f32    4608 B
    float*    offl  = (float*)(pool + 9216);      // [2][32][18] f32   4608 B
    _Float16* Ab    = (_Float16*)(pool + 13824);  // [2][32*AST] f16   9216 B (end 23040)
    float*    red   = (float*)pool;               // epilogue: [4][32][68] f32 = 34816 B

    int t = threadIdx.x;
    // bijective XCD swizzle (800 % 8 == 0)
    int tile = ((int)blockIdx.x & 7) * (NBLK / 8) + ((int)blockIdx.x >> 3);
    int pixbase = tile * PXB;
    int bb  = pixbase / HW;
    int hw0 = pixbase % HW;

    int lane = t & 63, wvi = t >> 6;
    int lm  = lane & 15;
    int kg8 = (lane >> 4) * 8;
    int ocq = wvi & 3, kh = wvi >> 2;

    int gpx = (t >> 3) & 31, q8 = t & 7, sub = t >> 8;   // gather roles

    const _Float16* xtb = xt + (size_t)bb * HW * CH;

    // ---- phase 1: offset conv via MFMA, k-split across waves ----
    // wave: pxf = wvi&1 (16 px), ocf = (wvi>>1)&1, kh = wvi>>2 (4 of 8 cg groups)
    {
        int pxf = wvi & 1, ocf = (wvi >> 1) & 1;
        f32x4 oacc = (f32x4)0.f;
        int apx = hw0 + pxf * 16 + lm;
        int h = apx / WW, w = apx % WW;
        #pragma unroll
        for (int tap = 0; tap < KK; ++tap) {
            int ki = tap / 3, kj = tap % 3;
            int yy = h + ki - 1, xx = w + kj - 1;
            bool ok = (yy >= 0) && (yy < HH) && (xx >= 0) && (xx < WW);
            const _Float16* asrc = xtb + (size_t)(yy * WW + xx) * CH + kg8;
            const _Float16* bsrc = wop + ((size_t)(tap * 8 * 32) + ocf * 16 + lm) * 32 + kg8;
            #pragma unroll
            for (int cgi = 0; cgi < 4; ++cgi) {
                int cg = kh * 4 + cgi;
                half8 a = {0, 0, 0, 0, 0, 0, 0, 0};
                if (ok) a = *(const half8*)(asrc + cg * 32);
                half8 b = *(const half8*)(bsrc + cg * 1024);
                oacc = __builtin_amdgcn_mfma_f32_16x16x32_f16(a, b, oacc, 0, 0, 0);
            }
        }
        int prow = pxf * 16 + (lane >> 4) * 4;
        int oc = ocf * 16 + lm;
        if (oc < CO) {
            #pragma unroll
            for (int r = 0; r < 4; ++r)
                offl[(kh * 32 + prow + r) * CO + oc] = oacc[r];
        }
    }
    __syncthreads();

    // ---- phase 2: bilinear corners/weights: 32 px x 9 taps ----
    if (t < PXB * KK) {
        int p = t / KK, tap = t % KK;
        int hw = pixbase % HW + p;
        int hc = hw / WW, wc = hw % WW;
        float dy = offl[p * CO + 2 * tap] + offl[(32 + p) * CO + 2 * tap] + obias[2 * tap];
        float dx = offl[p * CO + 2 * tap + 1] + offl[(32 + p) * CO + 2 * tap + 1] + obias[2 * tap + 1];
        int ki = tap / 3, kj = tap % 3;
        float py = dy + (float)(hc - 1 + ki);
        float px = dx + (float)(wc - 1 + kj);
        float y0f = floorf(py), x0f = floorf(px);
        float wy = py - y0f, wx = px - x0f;
        int y0 = (int)y0f, x0 = (int)x0f;
        #pragma unroll
        for (int cy = 0; cy < 2; ++cy)
            #pragma unroll
            for (int cx = 0; cx < 2; ++cx) {
                int yy = y0 + cy, xx = x0 + cx;
                bool okc = (yy >= 0) && (yy < HH) && (xx >= 0) && (xx < WW);
                int yc = min(max(yy, 0), HH - 1);
                int xc = min(max(xx, 0), WW - 1);
                float wgt = (cy ? wy : 1.f - wy) * (cx ? wx : 1.f - wx);
                cbase[(p * KK + tap) * 4 + cy * 2 + cx] = (yc * WW + xc) * CH;
                cwt[(p * KK + tap) * 4 + cy * 2 + cx]   = okc ? wgt : 0.f;
            }
    }
    __syncthreads();

    // ---- gather prologue: interval 0 (chunks 0,1) into Ab[0] ----
    {
        int q = sub;                       // tap 0, cg = sub
        const int*   cb = cbase + (gpx * KK + (q >> 3)) * 4;
        const float* cw = cwt   + (gpx * KK + (q >> 3)) * 4;
        int cg = q & 7;
        half4 vv = {0, 0, 0, 0};
        #pragma unroll
        for (int cn = 0; cn < 4; ++cn) {
            half4 a = *(const half4*)(xtb + cb[cn] + cg * 32 + q8 * 4);
            vv += a * (_Float16)cw[cn];
        }
        *(half4*)(Ab + gpx * AST + sub * 32 + q8 * 4) = vv;
    }

    f32x4 acc[2][4];
    #pragma unroll
    for (int mm = 0; mm < 2; ++mm)
        #pragma unroll
        for (int nn = 0; nn < 4; ++nn) acc[mm][nn] = (f32x4)0.f;

    // ---- main loop: 36 K64-intervals, single barrier each ----
    for (int i = 0; i < NIV; ++i) {
        int buf = i & 1;
        __syncthreads();

        // B fragments: coalesced 1 KB global reads (L2-resident), no LDS
        half8 bf[4];
        {
            const _Float16* wbase = wpk3 +
                ((((size_t)i * 4 + ocq) * 2 + kh) * 4) * 512 + lane * 8;
            #pragma unroll
            for (int nn = 0; nn < 4; ++nn)
                bf[nn] = *(const half8*)(wbase + nn * 512);
        }

        // issue next-interval gather loads early
        half4 pre[4];
        float pw4[4];
        if (i < NIV - 1) {
            int qn = 2 * i + 2 + sub;
            const int*   cb = cbase + (gpx * KK + (qn >> 3)) * 4;
            const float* cw = cwt   + (gpx * KK + (qn >> 3)) * 4;
            int cg = qn & 7;
            #pragma unroll
            for (int cn = 0; cn < 4; ++cn) {
                pre[cn] = *(const half4*)(xtb + cb[cn] + cg * 32 + q8 * 4);
                pw4[cn] = cw[cn];
            }
        }

        // A fragments from LDS (k-half of this wave)
        half8 af[2];
        #pragma unroll
        for (int mm = 0; mm < 2; ++mm)
            af[mm] = *(const half8*)(Ab + buf * (PXB * AST) + (mm * 16 + lm) * AST + kh * 32 + kg8);

        #pragma unroll
        for (int mm = 0; mm < 2; ++mm)
            #pragma unroll
            for (int nn = 0; nn < 4; ++nn)
                acc[mm][nn] = __builtin_amdgcn_mfma_f32_16x16x32_f16(af[mm], bf[nn], acc[mm][nn], 0, 0, 0);

        // blend + write next A (write-late, other buffer)
        if (i < NIV - 1) {
            half4 vv = {0, 0, 0, 0};
            #pragma unroll
            for (int cn = 0; cn < 4; ++cn) vv += pre[cn] * (_Float16)pw4[cn];
            *(half4*)(Ab + (buf ^ 1) * (PXB * AST) + gpx * AST + sub * 32 + q8 * 4) = vv;
        }
    }

    // ---- k-split reduction: waves 4-7 (kh=1) dump acc; waves 0-3 add ----
    __syncthreads();   // all MFMA/A-reads done before pool reuse
    if (wvi >= 4) {
        float* rw = red + (size_t)(wvi - 4) * (PXB * 68);
        #pragma unroll
        for (int mm = 0; mm < 2; ++mm)
            #pragma unroll
            for (int nn = 0; nn < 4; ++nn)
                #pragma unroll
                for (int r = 0; r < 4; ++r)
                    rw[(mm * 16 + (lane >> 4) * 4 + r) * 68 + nn * 16 + lm] = acc[mm][nn][r];
    }
    __syncthreads();
    if (wvi < 4) {
        const float* rr = red + (size_t)wvi * (PXB * 68);   // wave wvi+4 has same ocq
        const float* xb2  = x   + (size_t)bb * CH * HW;
        float*       outb = out + (size_t)bb * CH * HW;
        #pragma unroll
        for (int nn = 0; nn < 4; ++nn) {
            int oc = wvi * 64 + nn * 16 + lm;
            float sc = gamma[oc] * rsqrtf(var[oc] + 1e-5f);
            float mn = mean[oc], bt = beta[oc];
            const float* xr   = xb2  + (size_t)oc * HW + hw0;
            float*       orow = outb + (size_t)oc * HW + hw0;
            #pragma unroll
            for (int mm = 0; mm < 2; ++mm) {
                int pb = mm * 16 + (lane >> 4) * 4;
                #pragma unroll
                for (int r = 0; r < 4; ++r) {
                    float yv = acc[mm][nn][r] + rr[(pb + r) * 68 + nn * 16 + lm];
                    yv = (yv - mn) * sc + bt;
                    float s = yv * __builtin_amdgcn_rcpf(1.f + __expf(-yv));
                    orow[pb + r] = xr[pb + r] + s;
                }
            }
        }
    }
}

extern "C" void kernel_launch(void* const* d_in, const int* in_sizes, int n_in,
                              void* d_out, int out_size, void* d_ws, size_t ws_size,
                              hipStream_t stream) {
    const float* x        = (const float*)d_in[0];
    const float* offset_w = (const float*)d_in[1];
    const float* offset_b = (const float*)d_in[2];
    const float* dcn_w    = (const float*)d_in[3];
    const float* gamma    = (const float*)d_in[4];
    const float* beta     = (const float*)d_in[5];
    const float* mean     = (const float*)d_in[6];
    const float* var      = (const float*)d_in[7];
    float* out = (float*)d_out;

    _Float16* xt   = (_Float16*)d_ws;                    // NPIX*CH f16        = 13,107,200 B
    _Float16* wpk3 = xt + (size_t)NPIX * CH;             // 36*16384 f16       =  1,179,648 B
    _Float16* wop  = wpk3 + (size_t)NIV * 16384;         // 72*32*32 f16       =    147,456 B

    k_transpose_x<<<dim3(HW / 32, CH / 32, BATCH), dim3(32, 8), 0, stream>>>(x, xt);
    k_pack_w3<<<(NIV * 16384 + 255) / 256, 256, 0, stream>>>(dcn_w, wpk3);
    k_pack_ow<<<(NCHUNK * 32 * 32 + 255) / 256, 256, 0, stream>>>(offset_w, wop);
    k_main<<<NBLK, 512, 0, stream>>>(x, xt, wpk3, wop, offset_b,
                                     gamma, beta, mean, var, out);
}

// Round 7
// 128.661 us; speedup vs baseline: 1.1605x; 1.1605x over previous
//
#include <hip/hip_runtime.h>
#include <math.h>
#include <stdint.h>

#define BATCH 4
#define CH    256
#define HH    80
#define WW    80
#define HW    (HH*WW)        // 6400
#define NPIX  (BATCH*HW)     // 25600
#define KK    9
#define CO    18             // 2*K*K offset channels
#define NCHUNK 72            // 9 taps * 8 groups of 32 channels
#define NIV   36             // K=64 intervals
#define PXB   64             // pixels per k_main block
#define NBLK  (NPIX/PXB)     // 400 blocks
#define AST   72             // A LDS row stride in halves (144 B)

typedef _Float16 half8 __attribute__((ext_vector_type(8)));
typedef float    f32x4 __attribute__((ext_vector_type(4)));

// ---------------- x NCHW f32 -> xt NHWC f16 ----------------
__global__ __launch_bounds__(256) void k_transpose_x(const float* __restrict__ x,
                                                     _Float16* __restrict__ xt) {
    __shared__ float tile[32][33];
    int b  = blockIdx.z;
    int c0 = blockIdx.y * 32;
    int p0 = blockIdx.x * 32;
    int tx = threadIdx.x;   // 0..31
    int ty = threadIdx.y;   // 0..7
    const float* xb = x + (size_t)b * CH * HW;
    #pragma unroll
    for (int i = 0; i < 32; i += 8)
        tile[ty + i][tx] = xb[(size_t)(c0 + ty + i) * HW + p0 + tx];
    __syncthreads();
    _Float16* xtb = xt + (size_t)b * HW * CH;
    #pragma unroll
    for (int i = 0; i < 32; i += 8)
        xtb[(size_t)(p0 + ty + i) * CH + c0 + tx] = (_Float16)tile[tx][ty + i];
}

// -------- dcn_w [o][c][tap] f32 -> wpk3 [NIV][4 ocq][2 ks][4 nn][64 lane][8] f16 --------
__global__ __launch_bounds__(256) void k_pack_w3(const float* __restrict__ w,
                                                 _Float16* __restrict__ wp) {
    int idx = blockIdx.x * 256 + threadIdx.x;
    if (idx >= NIV * 4 * 2 * 4 * 64 * 8) return;
    int e    = idx & 7;
    int lane = (idx >> 3) & 63;
    int nn   = (idx >> 9) & 3;
    int ks   = (idx >> 11) & 1;
    int ocq  = (idx >> 12) & 3;
    int iv   = idx >> 14;
    int oc = ocq * 64 + nn * 16 + (lane & 15);
    int kl = ks * 32 + (lane >> 4) * 8 + e;
    int kg = iv * 64 + kl;
    int q  = kg >> 5;
    int tap = q >> 3;
    int c   = (q & 7) * 32 + (kg & 31);
    wp[idx] = (_Float16)w[((size_t)oc * CH + c) * KK + tap];
}

// -------- offset_w [18][256][9] f32 -> wopf [72 chunk][2 nf][64 lane][8] f16 --------
__global__ __launch_bounds__(256) void k_pack_wopf(const float* __restrict__ ow,
                                                   _Float16* __restrict__ wp) {
    int idx = blockIdx.x * 256 + threadIdx.x;
    if (idx >= NCHUNK * 2 * 64 * 8) return;
    int e    = idx & 7;
    int lane = (idx >> 3) & 63;
    int nf   = (idx >> 9) & 1;
    int q    = idx >> 10;
    int oc  = nf * 16 + (lane & 15);
    int kic = (lane >> 4) * 8 + e;
    int tap = q >> 3;
    int c   = (q & 7) * 32 + kic;
    float v = (oc < CO) ? ow[((size_t)oc * CH + c) * KK + tap] : 0.f;
    wp[idx] = (_Float16)v;
}

// ---------------- offset conv via MFMA, barrier-free, K-split x4 ----------------
// grid (400, 4); block 256 = 4 waves; wave wvi -> 16 px; k-slice ks -> chunks [18*ks,18*ks+18)
__global__ __launch_bounds__(256) void k_offset(const _Float16* __restrict__ xt,
                                                const _Float16* __restrict__ wopf,
                                                float* __restrict__ off4) {
    int t = threadIdx.x, lane = t & 63, wvi = t >> 6;
    int lm = lane & 15, kg8 = (lane >> 4) * 8;
    int ksl = blockIdx.y;
    int pixbase = blockIdx.x * 64;
    int bb = pixbase / HW;
    int apx = pixbase % HW + wvi * 16 + lm;
    int h = apx / WW, w = apx % WW;
    const _Float16* xtb = xt + (size_t)bb * HW * CH;
    f32x4 acc0 = (f32x4)0.f, acc1 = (f32x4)0.f;
    #pragma unroll
    for (int qq = 0; qq < 18; ++qq) {
        int q = ksl * 18 + qq;
        int tap = q >> 3, cg = q & 7;
        int ki = tap / 3, kj = tap % 3;
        int yy = h + ki - 1, xx = w + kj - 1;
        bool ok = (yy >= 0) && (yy < HH) && (xx >= 0) && (xx < WW);
        int yc = min(max(yy, 0), HH - 1), xc = min(max(xx, 0), WW - 1);
        half8 a = {0, 0, 0, 0, 0, 0, 0, 0};
        if (ok) a = *(const half8*)(xtb + (size_t)(yc * WW + xc) * CH + cg * 32 + kg8);
        const _Float16* wb = wopf + (size_t)q * 1024 + lane * 8;
        half8 b0 = *(const half8*)(wb);
        half8 b1 = *(const half8*)(wb + 512);
        acc0 = __builtin_amdgcn_mfma_f32_16x16x32_f16(a, b0, acc0, 0, 0, 0);
        acc1 = __builtin_amdgcn_mfma_f32_16x16x32_f16(a, b1, acc1, 0, 0, 0);
    }
    float* op = off4 + (size_t)ksl * NPIX * CO;
    int prow = (lane >> 4) * 4;
    #pragma unroll
    for (int r = 0; r < 4; ++r) {
        int pix = pixbase + wvi * 16 + prow + r;
        op[(size_t)pix * CO + lm] = acc0[r];
        if (lm < CO - 16) op[(size_t)pix * CO + 16 + lm] = acc1[r];
    }
}

// ---------------- bilinear corners/weights precompute ----------------
__global__ __launch_bounds__(256) void k_corners(const float* __restrict__ off4,
                                                 const float* __restrict__ obias,
                                                 int4* __restrict__ cbg,
                                                 float4* __restrict__ cwg) {
    int task = blockIdx.x * 256 + threadIdx.x;
    if (task >= NPIX * KK) return;
    int pix = task / KK, tap = task - pix * KK;
    float dy = obias[2 * tap], dx = obias[2 * tap + 1];
    #pragma unroll
    for (int ks = 0; ks < 4; ++ks) {
        dy += off4[(size_t)ks * NPIX * CO + (size_t)pix * CO + 2 * tap];
        dx += off4[(size_t)ks * NPIX * CO + (size_t)pix * CO + 2 * tap + 1];
    }
    int hw = pix % HW, hc = hw / WW, wc = hw % WW;
    int ki = tap / 3, kj = tap % 3;
    float py = dy + (float)(hc - 1 + ki);
    float px = dx + (float)(wc - 1 + kj);
    float y0f = floorf(py), x0f = floorf(px);
    float wy = py - y0f, wx = px - x0f;
    int y0 = (int)y0f, x0 = (int)x0f;
    int cb[4]; float cw[4];
    #pragma unroll
    for (int cy = 0; cy < 2; ++cy)
        #pragma unroll
        for (int cx = 0; cx < 2; ++cx) {
            int yy = y0 + cy, xx = x0 + cx;
            bool okc = (yy >= 0) && (yy < HH) && (xx >= 0) && (xx < WW);
            int yc = min(max(yy, 0), HH - 1);
            int xc = min(max(xx, 0), WW - 1);
            float wgt = (cy ? wy : 1.f - wy) * (cx ? wx : 1.f - wx);
            cb[cy * 2 + cx] = (yc * WW + xc) * CH;
            cw[cy * 2 + cx] = okc ? wgt : 0.f;
        }
    cbg[task] = make_int4(cb[0], cb[1], cb[2], cb[3]);
    cwg[task] = make_float4(cw[0], cw[1], cw[2], cw[3]);
}

// ---------------- gather + MFMA GEMM + BN/SiLU/residual ----------------
// 512 thr = 8 waves = 4 ocq x 2 pg; block = 64 px x 256 oc; wave = 32px x 64oc x full K
__global__ __launch_bounds__(512) void k_main(const float* __restrict__ x,
                                              const _Float16* __restrict__ xt,
                                              const _Float16* __restrict__ wpk3,
                                              const int4* __restrict__ cbg,
                                              const float4* __restrict__ cwg,
                                              const float* __restrict__ gamma,
                                              const float* __restrict__ beta,
                                              const float* __restrict__ mean,
                                              const float* __restrict__ var,
                                              float* __restrict__ out) {
    __shared__ _Float16 Ab[2][PXB * AST];   // 18432 B

    int t = threadIdx.x, lane = t & 63, wvi = t >> 6;
    int lm = lane & 15, kg8 = (lane >> 4) * 8;
    int ocq = wvi & 3, pg = wvi >> 2;
    int tile = ((int)blockIdx.x & 7) * (NBLK / 8) + ((int)blockIdx.x >> 3);
    int pixbase = tile * PXB;
    int bb = pixbase / HW, hw0 = pixbase % HW;
    const _Float16* xtb = xt + (size_t)bb * HW * CH;

    int gpx = t >> 3, cq = t & 7;
    const int4*   cbp = cbg + (size_t)(pixbase + gpx) * KK;
    const float4* cwp = cwg + (size_t)(pixbase + gpx) * KK;
    int ko = (cq & 3) * 8;

    // prologue: gather interval 0 into Ab[0]
    {
        int chunk = cq >> 2;
        int4 cb = cbp[0];
        float4 cw = cwp[0];
        int cg = chunk & 7;
        int cba[4] = {cb.x, cb.y, cb.z, cb.w};
        float cwa[4] = {cw.x, cw.y, cw.z, cw.w};
        half8 v = {0, 0, 0, 0, 0, 0, 0, 0};
        #pragma unroll
        for (int cn = 0; cn < 4; ++cn) {
            half8 a = *(const half8*)(xtb + (size_t)cba[cn] + cg * 32 + ko);
            v += a * (_Float16)cwa[cn];
        }
        *(half8*)&Ab[0][gpx * AST + cq * 8] = v;
    }

    f32x4 acc[2][4];
    #pragma unroll
    for (int mm = 0; mm < 2; ++mm)
        #pragma unroll
        for (int nn = 0; nn < 4; ++nn) acc[mm][nn] = (f32x4)0.f;

    for (int i = 0; i < NIV; ++i) {
        int buf = i & 1;
        __syncthreads();

        // issue next-interval gather loads early
        half8 pre[4];
        float cwa[4];
        if (i < NIV - 1) {
            int chunk = 2 * (i + 1) + (cq >> 2);
            int tap = chunk >> 3, cg = chunk & 7;
            int4 ncb = cbp[tap];
            float4 ncw = cwp[tap];
            int cba[4] = {ncb.x, ncb.y, ncb.z, ncb.w};
            cwa[0] = ncw.x; cwa[1] = ncw.y; cwa[2] = ncw.z; cwa[3] = ncw.w;
            #pragma unroll
            for (int cn = 0; cn < 4; ++cn)
                pre[cn] = *(const half8*)(xtb + (size_t)cba[cn] + cg * 32 + ko);
        }

        // B fragments: lane-exact coalesced global reads (L2-resident)
        const _Float16* wb = wpk3 + (size_t)i * 16384 + ocq * 4096 + lane * 8;
        half8 bf[2][4];
        #pragma unroll
        for (int ks = 0; ks < 2; ++ks)
            #pragma unroll
            for (int nn = 0; nn < 4; ++nn)
                bf[ks][nn] = *(const half8*)(wb + ks * 2048 + nn * 512);

        // A fragments from LDS
        half8 af[2][2];
        #pragma unroll
        for (int mm = 0; mm < 2; ++mm)
            #pragma unroll
            for (int ks = 0; ks < 2; ++ks)
                af[mm][ks] = *(const half8*)&Ab[buf][(pg * 32 + mm * 16 + lm) * AST + ks * 32 + kg8];

        #pragma unroll
        for (int ks = 0; ks < 2; ++ks)
            #pragma unroll
            for (int mm = 0; mm < 2; ++mm)
                #pragma unroll
                for (int nn = 0; nn < 4; ++nn)
                    acc[mm][nn] = __builtin_amdgcn_mfma_f32_16x16x32_f16(af[mm][ks], bf[ks][nn], acc[mm][nn], 0, 0, 0);

        // blend + write next A (write-late)
        if (i < NIV - 1) {
            half8 v = {0, 0, 0, 0, 0, 0, 0, 0};
            #pragma unroll
            for (int cn = 0; cn < 4; ++cn) v += pre[cn] * (_Float16)cwa[cn];
            *(half8*)&Ab[buf ^ 1][gpx * AST + cq * 8] = v;
        }
    }

    // --- epilogue: BN + SiLU + residual ---
    const float* xb2  = x   + (size_t)bb * CH * HW;
    float*       outb = out + (size_t)bb * CH * HW;
    #pragma unroll
    for (int nn = 0; nn < 4; ++nn) {
        int oc = ocq * 64 + nn * 16 + lm;
        float sc = gamma[oc] * rsqrtf(var[oc] + 1e-5f);
        float mn = mean[oc], bt = beta[oc];
        const float* xr   = xb2  + (size_t)oc * HW + hw0;
        float*       orow = outb + (size_t)oc * HW + hw0;
        #pragma unroll
        for (int mm = 0; mm < 2; ++mm) {
            int pb2 = pg * 32 + mm * 16 + (lane >> 4) * 4;
            #pragma unroll
            for (int r = 0; r < 4; ++r) {
                float yv = (acc[mm][nn][r] - mn) * sc + bt;
                float s = yv * __builtin_amdgcn_rcpf(1.f + __expf(-yv));
                orow[pb2 + r] = xr[pb2 + r] + s;
            }
        }
    }
}

extern "C" void kernel_launch(void* const* d_in, const int* in_sizes, int n_in,
                              void* d_out, int out_size, void* d_ws, size_t ws_size,
                              hipStream_t stream) {
    const float* x        = (const float*)d_in[0];
    const float* offset_w = (const float*)d_in[1];
    const float* offset_b = (const float*)d_in[2];
    const float* dcn_w    = (const float*)d_in[3];
    const float* gamma    = (const float*)d_in[4];
    const float* beta     = (const float*)d_in[5];
    const float* mean     = (const float*)d_in[6];
    const float* var      = (const float*)d_in[7];
    float* out = (float*)d_out;

    _Float16* xt   = (_Float16*)d_ws;                    // 13,107,200 B
    _Float16* wpk3 = xt + (size_t)NPIX * CH;             //  1,179,648 B
    _Float16* wopf = wpk3 + (size_t)NIV * 16384;         //    147,456 B
    float*    off4 = (float*)(wopf + (size_t)NCHUNK * 1024);  // 4*NPIX*CO f32 = 7,372,800 B
    int4*     cbg  = (int4*)(off4 + (size_t)4 * NPIX * CO);   // 3,686,400 B
    float4*   cwg  = (float4*)(cbg + (size_t)NPIX * KK);      // 3,686,400 B

    k_transpose_x<<<dim3(HW / 32, CH / 32, BATCH), dim3(32, 8), 0, stream>>>(x, xt);
    k_pack_w3<<<(NIV * 16384 + 255) / 256, 256, 0, stream>>>(dcn_w, wpk3);
    k_pack_wopf<<<(NCHUNK * 1024 + 255) / 256, 256, 0, stream>>>(offset_w, wopf);
    k_offset<<<dim3(NBLK, 4), 256, 0, stream>>>(xt, wopf, off4);
    k_corners<<<(NPIX * KK + 255) / 256, 256, 0, stream>>>(off4, offset_b, cbg, cwg);
    k_main<<<NBLK, 512, 0, stream>>>(x, xt, wpk3, cbg, cwg,
                                     gamma, beta, mean, var, out);
}

// Round 8
// 113.682 us; speedup vs baseline: 1.3134x; 1.1318x over previous
//
#include <hip/hip_runtime.h>
#include <math.h>
#include <stdint.h>

#define BATCH 4
#define CH    256
#define HH    80
#define WW    80
#define HW    (HH*WW)        // 6400
#define NPIX  (BATCH*HW)     // 25600
#define KK    9
#define CO    18             // 2*K*K offset channels
#define NCHUNK 72            // 9 taps * 8 groups of 32 channels
#define NIV   36             // K=64 intervals
#define PXB   64             // pixels per k_main block
#define NBLK  (NPIX/PXB)     // 400 blocks
#define AST   72             // A LDS row stride in halves (144 B)

typedef _Float16 half8 __attribute__((ext_vector_type(8)));
typedef float    f32x4 __attribute__((ext_vector_type(4)));

// ---------------- x NCHW f32 -> xt NHWC f16 ----------------
__global__ __launch_bounds__(256) void k_transpose_x(const float* __restrict__ x,
                                                     _Float16* __restrict__ xt) {
    __shared__ float tile[32][33];
    int b  = blockIdx.z;
    int c0 = blockIdx.y * 32;
    int p0 = blockIdx.x * 32;
    int tx = threadIdx.x;   // 0..31
    int ty = threadIdx.y;   // 0..7
    const float* xb = x + (size_t)b * CH * HW;
    #pragma unroll
    for (int i = 0; i < 32; i += 8)
        tile[ty + i][tx] = xb[(size_t)(c0 + ty + i) * HW + p0 + tx];
    __syncthreads();
    _Float16* xtb = xt + (size_t)b * HW * CH;
    #pragma unroll
    for (int i = 0; i < 32; i += 8)
        xtb[(size_t)(p0 + ty + i) * CH + c0 + tx] = (_Float16)tile[tx][ty + i];
}

// -------- combined weight pack --------
// part 1: dcn_w [o][c][tap] -> wpk4 [NIV][8 og][2 ks][2 nn][64 lane][8 e] f16
// part 2: offset_w [18][256][9] -> wopf [72 chunk][2 nf][64 lane][8 e] f16
__global__ __launch_bounds__(256) void k_pack_all(const float* __restrict__ w,
                                                  const float* __restrict__ ow,
                                                  _Float16* __restrict__ wp,
                                                  _Float16* __restrict__ wpo) {
    int idx = blockIdx.x * 256 + threadIdx.x;
    if (idx < NIV * 16384) {
        int e    = idx & 7;
        int lane = (idx >> 3) & 63;
        int nn   = (idx >> 9) & 1;
        int ks   = (idx >> 10) & 1;
        int og   = (idx >> 11) & 7;
        int iv   = idx >> 14;
        int oc = og * 32 + nn * 16 + (lane & 15);
        int kl = ks * 32 + (lane >> 4) * 8 + e;
        int kg = iv * 64 + kl;
        int q  = kg >> 5;
        int tap = q >> 3;
        int c   = (q & 7) * 32 + (kg & 31);
        wp[idx] = (_Float16)w[((size_t)oc * CH + c) * KK + tap];
        return;
    }
    int idx2 = idx - NIV * 16384;
    if (idx2 >= NCHUNK * 1024) return;
    int e    = idx2 & 7;
    int lane = (idx2 >> 3) & 63;
    int nf   = (idx2 >> 9) & 1;
    int q    = idx2 >> 10;
    int oc  = nf * 16 + (lane & 15);
    int kic = (lane >> 4) * 8 + e;
    int tap = q >> 3;
    int c   = (q & 7) * 32 + kic;
    float v = (oc < CO) ? ow[((size_t)oc * CH + c) * KK + tap] : 0.f;
    wpo[idx2] = (_Float16)v;
}

// ---------------- offset conv via MFMA, barrier-free, K-split x4 ----------------
__global__ __launch_bounds__(256) void k_offset(const _Float16* __restrict__ xt,
                                                const _Float16* __restrict__ wopf,
                                                float* __restrict__ off4) {
    int t = threadIdx.x, lane = t & 63, wvi = t >> 6;
    int lm = lane & 15, kg8 = (lane >> 4) * 8;
    int ksl = blockIdx.y;
    int pixbase = blockIdx.x * 64;
    int bb = pixbase / HW;
    int apx = pixbase % HW + wvi * 16 + lm;
    int h = apx / WW, w = apx % WW;
    const _Float16* xtb = xt + (size_t)bb * HW * CH;
    f32x4 acc0 = (f32x4)0.f, acc1 = (f32x4)0.f;
    #pragma unroll
    for (int qq = 0; qq < 18; ++qq) {
        int q = ksl * 18 + qq;
        int tap = q >> 3, cg = q & 7;
        int ki = tap / 3, kj = tap % 3;
        int yy = h + ki - 1, xx = w + kj - 1;
        bool ok = (yy >= 0) && (yy < HH) && (xx >= 0) && (xx < WW);
        int yc = min(max(yy, 0), HH - 1), xc = min(max(xx, 0), WW - 1);
        half8 a = {0, 0, 0, 0, 0, 0, 0, 0};
        if (ok) a = *(const half8*)(xtb + (size_t)(yc * WW + xc) * CH + cg * 32 + kg8);
        const _Float16* wb = wopf + (size_t)q * 1024 + lane * 8;
        half8 b0 = *(const half8*)(wb);
        half8 b1 = *(const half8*)(wb + 512);
        acc0 = __builtin_amdgcn_mfma_f32_16x16x32_f16(a, b0, acc0, 0, 0, 0);
        acc1 = __builtin_amdgcn_mfma_f32_16x16x32_f16(a, b1, acc1, 0, 0, 0);
    }
    float* op = off4 + (size_t)ksl * NPIX * CO;
    int prow = (lane >> 4) * 4;
    #pragma unroll
    for (int r = 0; r < 4; ++r) {
        int pix = pixbase + wvi * 16 + prow + r;
        op[(size_t)pix * CO + lm] = acc0[r];
        if (lm < CO - 16) op[(size_t)pix * CO + 16 + lm] = acc1[r];
    }
}

// ---------------- bilinear corners/weights precompute ----------------
__global__ __launch_bounds__(256) void k_corners(const float* __restrict__ off4,
                                                 const float* __restrict__ obias,
                                                 int4* __restrict__ cbg,
                                                 float4* __restrict__ cwg) {
    int task = blockIdx.x * 256 + threadIdx.x;
    if (task >= NPIX * KK) return;
    int pix = task / KK, tap = task - pix * KK;
    float dy = obias[2 * tap], dx = obias[2 * tap + 1];
    #pragma unroll
    for (int ks = 0; ks < 4; ++ks) {
        dy += off4[(size_t)ks * NPIX * CO + (size_t)pix * CO + 2 * tap];
        dx += off4[(size_t)ks * NPIX * CO + (size_t)pix * CO + 2 * tap + 1];
    }
    int hw = pix % HW, hc = hw / WW, wc = hw % WW;
    int ki = tap / 3, kj = tap % 3;
    float py = dy + (float)(hc - 1 + ki);
    float px = dx + (float)(wc - 1 + kj);
    float y0f = floorf(py), x0f = floorf(px);
    float wy = py - y0f, wx = px - x0f;
    int y0 = (int)y0f, x0 = (int)x0f;
    int cb[4]; float cw[4];
    #pragma unroll
    for (int cy = 0; cy < 2; ++cy)
        #pragma unroll
        for (int cx = 0; cx < 2; ++cx) {
            int yy = y0 + cy, xx = x0 + cx;
            bool okc = (yy >= 0) && (yy < HH) && (xx >= 0) && (xx < WW);
            int yc = min(max(yy, 0), HH - 1);
            int xc = min(max(xx, 0), WW - 1);
            float wgt = (cy ? wy : 1.f - wy) * (cx ? wx : 1.f - wx);
            cb[cy * 2 + cx] = (yc * WW + xc) * CH;
            cw[cy * 2 + cx] = okc ? wgt : 0.f;
        }
    cbg[task] = make_int4(cb[0], cb[1], cb[2], cb[3]);
    cwg[task] = make_float4(cw[0], cw[1], cw[2], cw[3]);
}

// ---------------- gather + MFMA GEMM + BN/SiLU/residual ----------------
// 512 thr = 8 waves = 8 og; block = 64 px x 256 oc; wave = 64px x 32oc x full K
// B double-buffered in REGISTERS: interval i prefetches B(i+1); __syncthreads'
// vmcnt drain guarantees arrival, so MFMA never waits on vmem.
#define BODY(IV, BCUR, BNXT, RBUF, WBUF)                                           \
  {                                                                                \
    __syncthreads();                                                               \
    const int iv_ = (IV);                                                          \
    half8 pre[4]; float cwa[4];                                                    \
    if (iv_ < NIV - 1) {                                                           \
      const _Float16* wb = wpk4 + (size_t)(iv_ + 1) * 16384 + og * 2048 + lane * 8;\
      BNXT[0] = *(const half8*)(wb);                                               \
      BNXT[1] = *(const half8*)(wb + 512);                                         \
      BNXT[2] = *(const half8*)(wb + 1024);                                        \
      BNXT[3] = *(const half8*)(wb + 1536);                                        \
      int chunk = 2 * (iv_ + 1) + sub;                                             \
      int tap = chunk >> 3, cg = chunk & 7;                                        \
      int4 ncb = cbp[tap]; float4 ncw = cwp[tap];                                  \
      pre[0] = *(const half8*)(xtb + (size_t)ncb.x + cg * 32 + ko);                \
      pre[1] = *(const half8*)(xtb + (size_t)ncb.y + cg * 32 + ko);                \
      pre[2] = *(const half8*)(xtb + (size_t)ncb.z + cg * 32 + ko);                \
      pre[3] = *(const half8*)(xtb + (size_t)ncb.w + cg * 32 + ko);                \
      cwa[0] = ncw.x; cwa[1] = ncw.y; cwa[2] = ncw.z; cwa[3] = ncw.w;              \
    }                                                                              \
    _Pragma("unroll")                                                              \
    for (int mm = 0; mm < 4; ++mm) {                                               \
      half8 a0 = *(const half8*)&Ab[RBUF][(mm * 16 + lm) * AST + kg8];             \
      half8 a1 = *(const half8*)&Ab[RBUF][(mm * 16 + lm) * AST + 32 + kg8];        \
      acc[mm][0] = __builtin_amdgcn_mfma_f32_16x16x32_f16(a0, BCUR[0], acc[mm][0], 0, 0, 0); \
      acc[mm][1] = __builtin_amdgcn_mfma_f32_16x16x32_f16(a0, BCUR[1], acc[mm][1], 0, 0, 0); \
      acc[mm][0] = __builtin_amdgcn_mfma_f32_16x16x32_f16(a1, BCUR[2], acc[mm][0], 0, 0, 0); \
      acc[mm][1] = __builtin_amdgcn_mfma_f32_16x16x32_f16(a1, BCUR[3], acc[mm][1], 0, 0, 0); \
    }                                                                              \
    if (iv_ < NIV - 1) {                                                           \
      half8 v = pre[0] * (_Float16)cwa[0];                                         \
      v += pre[1] * (_Float16)cwa[1];                                              \
      v += pre[2] * (_Float16)cwa[2];                                              \
      v += pre[3] * (_Float16)cwa[3];                                              \
      *(half8*)&Ab[WBUF][gpx * AST + cq * 8] = v;                                  \
    }                                                                              \
  }

__global__ __launch_bounds__(512, 4) void k_main(const float* __restrict__ x,
                                                 const _Float16* __restrict__ xt,
                                                 const _Float16* __restrict__ wpk4,
                                                 const int4* __restrict__ cbg,
                                                 const float4* __restrict__ cwg,
                                                 const float* __restrict__ gamma,
                                                 const float* __restrict__ beta,
                                                 const float* __restrict__ mean,
                                                 const float* __restrict__ var,
                                                 float* __restrict__ out) {
    __shared__ _Float16 Ab[2][PXB * AST];   // 18432 B

    int t = threadIdx.x, lane = t & 63, og = t >> 6;
    int lm = lane & 15, kg8 = (lane >> 4) * 8;
    int tile = ((int)blockIdx.x & 7) * (NBLK / 8) + ((int)blockIdx.x >> 3);
    int pixbase = tile * PXB;
    int bb = pixbase / HW, hw0 = pixbase % HW;
    const _Float16* xtb = xt + (size_t)bb * HW * CH;

    int gpx = t >> 3, cq = t & 7;
    int sub = cq >> 2, ko = (cq & 3) * 8;
    const int4*   cbp = cbg + (size_t)(pixbase + gpx) * KK;
    const float4* cwp = cwg + (size_t)(pixbase + gpx) * KK;

    // prologue: B(0) -> regs; gather interval 0 (chunks 0,1) -> Ab[0]
    half8 bfA[4], bfB[4];
    {
        const _Float16* wb = wpk4 + og * 2048 + lane * 8;
        bfA[0] = *(const half8*)(wb);
        bfA[1] = *(const half8*)(wb + 512);
        bfA[2] = *(const half8*)(wb + 1024);
        bfA[3] = *(const half8*)(wb + 1536);
    }
    {
        int4 cb = cbp[0];
        float4 cw = cwp[0];
        int cg = sub;                       // chunks 0,1: tap 0
        half8 v = *(const half8*)(xtb + (size_t)cb.x + cg * 32 + ko) * (_Float16)cw.x;
        v += *(const half8*)(xtb + (size_t)cb.y + cg * 32 + ko) * (_Float16)cw.y;
        v += *(const half8*)(xtb + (size_t)cb.z + cg * 32 + ko) * (_Float16)cw.z;
        v += *(const half8*)(xtb + (size_t)cb.w + cg * 32 + ko) * (_Float16)cw.w;
        *(half8*)&Ab[0][gpx * AST + cq * 8] = v;
    }

    f32x4 acc[4][2];
    #pragma unroll
    for (int mm = 0; mm < 4; ++mm) {
        acc[mm][0] = (f32x4)0.f;
        acc[mm][1] = (f32x4)0.f;
    }

    for (int ii = 0; ii < NIV; ii += 2) {
        BODY(ii,     bfA, bfB, 0, 1)
        BODY(ii + 1, bfB, bfA, 1, 0)
    }

    // --- epilogue: BN + SiLU + residual ---
    const float* xb2  = x   + (size_t)bb * CH * HW;
    float*       outb = out + (size_t)bb * CH * HW;
    #pragma unroll
    for (int nn = 0; nn < 2; ++nn) {
        int oc = og * 32 + nn * 16 + lm;
        float sc = gamma[oc] * rsqrtf(var[oc] + 1e-5f);
        float mn = mean[oc], bt = beta[oc];
        const float* xr   = xb2  + (size_t)oc * HW + hw0;
        float*       orow = outb + (size_t)oc * HW + hw0;
        #pragma unroll
        for (int mm = 0; mm < 4; ++mm) {
            int pb2 = mm * 16 + (lane >> 4) * 4;
            #pragma unroll
            for (int r = 0; r < 4; ++r) {
                float yv = (acc[mm][nn][r] - mn) * sc + bt;
                float s = yv * __builtin_amdgcn_rcpf(1.f + __expf(-yv));
                orow[pb2 + r] = xr[pb2 + r] + s;
            }
        }
    }
}

extern "C" void kernel_launch(void* const* d_in, const int* in_sizes, int n_in,
                              void* d_out, int out_size, void* d_ws, size_t ws_size,
                              hipStream_t stream) {
    const float* x        = (const float*)d_in[0];
    const float* offset_w = (const float*)d_in[1];
    const float* offset_b = (const float*)d_in[2];
    const float* dcn_w    = (const float*)d_in[3];
    const float* gamma    = (const float*)d_in[4];
    const float* beta     = (const float*)d_in[5];
    const float* mean     = (const float*)d_in[6];
    const float* var      = (const float*)d_in[7];
    float* out = (float*)d_out;

    _Float16* xt   = (_Float16*)d_ws;                    // 13,107,200 B
    _Float16* wpk4 = xt + (size_t)NPIX * CH;             //  1,179,648 B
    _Float16* wopf = wpk4 + (size_t)NIV * 16384;         //    147,456 B
    float*    off4 = (float*)(wopf + (size_t)NCHUNK * 1024);  // 7,372,800 B
    int4*     cbg  = (int4*)(off4 + (size_t)4 * NPIX * CO);   // 3,686,400 B
    float4*   cwg  = (float4*)(cbg + (size_t)NPIX * KK);      // 3,686,400 B

    k_transpose_x<<<dim3(HW / 32, CH / 32, BATCH), dim3(32, 8), 0, stream>>>(x, xt);
    k_pack_all<<<(NIV * 16384 + NCHUNK * 1024 + 255) / 256, 256, 0, stream>>>(dcn_w, offset_w, wpk4, wopf);
    k_offset<<<dim3(NBLK, 4), 256, 0, stream>>>(xt, wopf, off4);
    k_corners<<<(NPIX * KK + 255) / 256, 256, 0, stream>>>(off4, offset_b, cbg, cwg);
    k_main<<<NBLK, 512, 0, stream>>>(x, xt, wpk4, cbg, cwg,
                                     gamma, beta, mean, var, out);
}

// Round 9
// 96.407 us; speedup vs baseline: 1.5488x; 1.1792x over previous
//
#include <hip/hip_runtime.h>
#include <math.h>
#include <stdint.h>

#define BATCH 4
#define CH    256
#define HH    80
#define WW    80
#define HW    (HH*WW)        // 6400
#define NPIX  (BATCH*HW)     // 25600
#define KK    9
#define CO    18             // 2*K*K offset channels
#define NCHUNK 72            // 9 taps * 8 groups of 32 channels
#define NIV   36             // K=64 intervals
#define PXB   64             // pixels per k_main block
#define NBLK  (NPIX/PXB)     // 400 blocks
#define AST   72             // A LDS row stride in halves (144 B)

typedef _Float16 half8 __attribute__((ext_vector_type(8)));
typedef float    f32x4 __attribute__((ext_vector_type(4)));

// ---------------- x NCHW f32 -> xt NHWC f16 ----------------
__global__ __launch_bounds__(256) void k_transpose_x(const float* __restrict__ x,
                                                     _Float16* __restrict__ xt) {
    __shared__ float tile[32][33];
    int b  = blockIdx.z;
    int c0 = blockIdx.y * 32;
    int p0 = blockIdx.x * 32;
    int tx = threadIdx.x;   // 0..31
    int ty = threadIdx.y;   // 0..7
    const float* xb = x + (size_t)b * CH * HW;
    #pragma unroll
    for (int i = 0; i < 32; i += 8)
        tile[ty + i][tx] = xb[(size_t)(c0 + ty + i) * HW + p0 + tx];
    __syncthreads();
    _Float16* xtb = xt + (size_t)b * HW * CH;
    #pragma unroll
    for (int i = 0; i < 32; i += 8)
        xtb[(size_t)(p0 + ty + i) * CH + c0 + tx] = (_Float16)tile[tx][ty + i];
}

// -------- combined weight pack --------
__global__ __launch_bounds__(256) void k_pack_all(const float* __restrict__ w,
                                                  const float* __restrict__ ow,
                                                  _Float16* __restrict__ wp,
                                                  _Float16* __restrict__ wpo) {
    int idx = blockIdx.x * 256 + threadIdx.x;
    if (idx < NIV * 16384) {
        int e    = idx & 7;
        int lane = (idx >> 3) & 63;
        int nn   = (idx >> 9) & 1;
        int ks   = (idx >> 10) & 1;
        int og   = (idx >> 11) & 7;
        int iv   = idx >> 14;
        int oc = og * 32 + nn * 16 + (lane & 15);
        int kl = ks * 32 + (lane >> 4) * 8 + e;
        int kg = iv * 64 + kl;
        int q  = kg >> 5;
        int tap = q >> 3;
        int c   = (q & 7) * 32 + (kg & 31);
        wp[idx] = (_Float16)w[((size_t)oc * CH + c) * KK + tap];
        return;
    }
    int idx2 = idx - NIV * 16384;
    if (idx2 >= NCHUNK * 1024) return;
    int e    = idx2 & 7;
    int lane = (idx2 >> 3) & 63;
    int nf   = (idx2 >> 9) & 1;
    int q    = idx2 >> 10;
    int oc  = nf * 16 + (lane & 15);
    int kic = (lane >> 4) * 8 + e;
    int tap = q >> 3;
    int c   = (q & 7) * 32 + kic;
    float v = (oc < CO) ? ow[((size_t)oc * CH + c) * KK + tap] : 0.f;
    wpo[idx2] = (_Float16)v;
}

// ---------------- offset conv via MFMA, barrier-free, K-split x4 ----------------
__global__ __launch_bounds__(256) void k_offset(const _Float16* __restrict__ xt,
                                                const _Float16* __restrict__ wopf,
                                                float* __restrict__ off4) {
    int t = threadIdx.x, lane = t & 63, wvi = t >> 6;
    int lm = lane & 15, kg8 = (lane >> 4) * 8;
    int ksl = blockIdx.y;
    int pixbase = blockIdx.x * 64;
    int bb = pixbase / HW;
    int apx = pixbase % HW + wvi * 16 + lm;
    int h = apx / WW, w = apx % WW;
    const _Float16* xtb = xt + (size_t)bb * HW * CH;
    f32x4 acc0 = (f32x4)0.f, acc1 = (f32x4)0.f;
    #pragma unroll
    for (int qq = 0; qq < 18; ++qq) {
        int q = ksl * 18 + qq;
        int tap = q >> 3, cg = q & 7;
        int ki = tap / 3, kj = tap % 3;
        int yy = h + ki - 1, xx = w + kj - 1;
        bool ok = (yy >= 0) && (yy < HH) && (xx >= 0) && (xx < WW);
        int yc = min(max(yy, 0), HH - 1), xc = min(max(xx, 0), WW - 1);
        half8 a = {0, 0, 0, 0, 0, 0, 0, 0};
        if (ok) a = *(const half8*)(xtb + (size_t)(yc * WW + xc) * CH + cg * 32 + kg8);
        const _Float16* wb = wopf + (size_t)q * 1024 + lane * 8;
        half8 b0 = *(const half8*)(wb);
        half8 b1 = *(const half8*)(wb + 512);
        acc0 = __builtin_amdgcn_mfma_f32_16x16x32_f16(a, b0, acc0, 0, 0, 0);
        acc1 = __builtin_amdgcn_mfma_f32_16x16x32_f16(a, b1, acc1, 0, 0, 0);
    }
    float* op = off4 + (size_t)ksl * NPIX * CO;
    int prow = (lane >> 4) * 4;
    #pragma unroll
    for (int r = 0; r < 4; ++r) {
        int pix = pixbase + wvi * 16 + prow + r;
        op[(size_t)pix * CO + lm] = acc0[r];
        if (lm < CO - 16) op[(size_t)pix * CO + 16 + lm] = acc1[r];
    }
}

// ---------------- gather + MFMA GEMM + BN/SiLU/residual ----------------
// 512 thr = 8 waves = 8 og; block = 64 px x 256 oc; wave = 64px x 32oc x full K
// B double-buffered in registers; corners/weights in LDS (broadcast reads).
#define BODY(IV, BCUR, BNXT, RBUF, WBUF)                                           \
  {                                                                                \
    __syncthreads();                                                               \
    const int iv_ = (IV);                                                          \
    half8 pre[4]; float cwa[4];                                                    \
    if (iv_ < NIV - 1) {                                                           \
      const _Float16* wb = wpk4 + (size_t)(iv_ + 1) * 16384 + og * 2048 + lane * 8;\
      BNXT[0] = *(const half8*)(wb);                                               \
      BNXT[1] = *(const half8*)(wb + 512);                                         \
      BNXT[2] = *(const half8*)(wb + 1024);                                        \
      BNXT[3] = *(const half8*)(wb + 1536);                                        \
      int chunk = 2 * (iv_ + 1) + sub;                                             \
      int tap = chunk >> 3, cg = chunk & 7;                                        \
      int4 ncb = cbl[gpx][tap]; float4 ncw = cwl[gpx][tap];                        \
      pre[0] = *(const half8*)(xtb + (size_t)ncb.x + cg * 32 + ko);                \
      pre[1] = *(const half8*)(xtb + (size_t)ncb.y + cg * 32 + ko);                \
      pre[2] = *(const half8*)(xtb + (size_t)ncb.z + cg * 32 + ko);                \
      pre[3] = *(const half8*)(xtb + (size_t)ncb.w + cg * 32 + ko);                \
      cwa[0] = ncw.x; cwa[1] = ncw.y; cwa[2] = ncw.z; cwa[3] = ncw.w;              \
    }                                                                              \
    __builtin_amdgcn_s_setprio(1);                                                 \
    _Pragma("unroll")                                                              \
    for (int mm = 0; mm < 4; ++mm) {                                               \
      half8 a0 = *(const half8*)&Ab[RBUF][(mm * 16 + lm) * AST + kg8];             \
      half8 a1 = *(const half8*)&Ab[RBUF][(mm * 16 + lm) * AST + 32 + kg8];        \
      acc[mm][0] = __builtin_amdgcn_mfma_f32_16x16x32_f16(a0, BCUR[0], acc[mm][0], 0, 0, 0); \
      acc[mm][1] = __builtin_amdgcn_mfma_f32_16x16x32_f16(a0, BCUR[1], acc[mm][1], 0, 0, 0); \
      acc[mm][0] = __builtin_amdgcn_mfma_f32_16x16x32_f16(a1, BCUR[2], acc[mm][0], 0, 0, 0); \
      acc[mm][1] = __builtin_amdgcn_mfma_f32_16x16x32_f16(a1, BCUR[3], acc[mm][1], 0, 0, 0); \
    }                                                                              \
    __builtin_amdgcn_s_setprio(0);                                                 \
    if (iv_ < NIV - 1) {                                                           \
      half8 v = pre[0] * (_Float16)cwa[0];                                         \
      v += pre[1] * (_Float16)cwa[1];                                              \
      v += pre[2] * (_Float16)cwa[2];                                              \
      v += pre[3] * (_Float16)cwa[3];                                              \
      *(half8*)&Ab[WBUF][gpx * AST + cq * 8] = v;                                  \
    }                                                                              \
  }

__global__ __launch_bounds__(512, 4) void k_main(const float* __restrict__ x,
                                                 const _Float16* __restrict__ xt,
                                                 const _Float16* __restrict__ wpk4,
                                                 const float* __restrict__ off4,
                                                 const float* __restrict__ obias,
                                                 const float* __restrict__ gamma,
                                                 const float* __restrict__ beta,
                                                 const float* __restrict__ mean,
                                                 const float* __restrict__ var,
                                                 float* __restrict__ out) {
    __shared__ _Float16 Ab[2][PXB * AST];   // 18432 B
    __shared__ int4     cbl[PXB][KK];       // 9216 B
    __shared__ float4   cwl[PXB][KK];       // 9216 B

    int t = threadIdx.x, lane = t & 63, og = t >> 6;
    int lm = lane & 15, kg8 = (lane >> 4) * 8;
    int tile = ((int)blockIdx.x & 7) * (NBLK / 8) + ((int)blockIdx.x >> 3);
    int pixbase = tile * PXB;
    int bb = pixbase / HW, hw0 = pixbase % HW;
    const _Float16* xtb = xt + (size_t)bb * HW * CH;

    // ---- phase 1: bilinear corners/weights for 64 px x 9 taps -> LDS ----
    for (int task = t; task < PXB * KK; task += 512) {
        int p = task / KK, tap = task - (task / KK) * KK;
        int pix = pixbase + p;
        float dy = obias[2 * tap], dx = obias[2 * tap + 1];
        #pragma unroll
        for (int ks = 0; ks < 4; ++ks) {
            dy += off4[(size_t)ks * NPIX * CO + (size_t)pix * CO + 2 * tap];
            dx += off4[(size_t)ks * NPIX * CO + (size_t)pix * CO + 2 * tap + 1];
        }
        int hw = pix % HW, hc = hw / WW, wc = hw % WW;
        int ki = tap / 3, kj = tap % 3;
        float py = dy + (float)(hc - 1 + ki);
        float px = dx + (float)(wc - 1 + kj);
        float y0f = floorf(py), x0f = floorf(px);
        float wy = py - y0f, wx = px - x0f;
        int y0 = (int)y0f, x0 = (int)x0f;
        int cb[4]; float cw[4];
        #pragma unroll
        for (int cy = 0; cy < 2; ++cy)
            #pragma unroll
            for (int cx = 0; cx < 2; ++cx) {
                int yy = y0 + cy, xx = x0 + cx;
                bool okc = (yy >= 0) && (yy < HH) && (xx >= 0) && (xx < WW);
                int yc = min(max(yy, 0), HH - 1);
                int xc = min(max(xx, 0), WW - 1);
                float wgt = (cy ? wy : 1.f - wy) * (cx ? wx : 1.f - wx);
                cb[cy * 2 + cx] = (yc * WW + xc) * CH;
                cw[cy * 2 + cx] = okc ? wgt : 0.f;
            }
        cbl[p][tap] = make_int4(cb[0], cb[1], cb[2], cb[3]);
        cwl[p][tap] = make_float4(cw[0], cw[1], cw[2], cw[3]);
    }
    __syncthreads();

    int gpx = t >> 3, cq = t & 7;
    int sub = cq >> 2, ko = (cq & 3) * 8;

    // prologue: B(0) -> regs; gather interval 0 (chunks 0,1) -> Ab[0]
    half8 bfA[4], bfB[4];
    {
        const _Float16* wb = wpk4 + og * 2048 + lane * 8;
        bfA[0] = *(const half8*)(wb);
        bfA[1] = *(const half8*)(wb + 512);
        bfA[2] = *(const half8*)(wb + 1024);
        bfA[3] = *(const half8*)(wb + 1536);
    }
    {
        int4 cb = cbl[gpx][0];
        float4 cw = cwl[gpx][0];
        int cg = sub;                       // chunks 0,1: tap 0
        half8 v = *(const half8*)(xtb + (size_t)cb.x + cg * 32 + ko) * (_Float16)cw.x;
        v += *(const half8*)(xtb + (size_t)cb.y + cg * 32 + ko) * (_Float16)cw.y;
        v += *(const half8*)(xtb + (size_t)cb.z + cg * 32 + ko) * (_Float16)cw.z;
        v += *(const half8*)(xtb + (size_t)cb.w + cg * 32 + ko) * (_Float16)cw.w;
        *(half8*)&Ab[0][gpx * AST + cq * 8] = v;
    }

    f32x4 acc[4][2];
    #pragma unroll
    for (int mm = 0; mm < 4; ++mm) {
        acc[mm][0] = (f32x4)0.f;
        acc[mm][1] = (f32x4)0.f;
    }

    for (int ii = 0; ii < NIV; ii += 2) {
        BODY(ii,     bfA, bfB, 0, 1)
        BODY(ii + 1, bfB, bfA, 1, 0)
    }

    // --- epilogue: BN + SiLU + residual ---
    const float* xb2  = x   + (size_t)bb * CH * HW;
    float*       outb = out + (size_t)bb * CH * HW;
    #pragma unroll
    for (int nn = 0; nn < 2; ++nn) {
        int oc = og * 32 + nn * 16 + lm;
        float sc = gamma[oc] * rsqrtf(var[oc] + 1e-5f);
        float mn = mean[oc], bt = beta[oc];
        const float* xr   = xb2  + (size_t)oc * HW + hw0;
        float*       orow = outb + (size_t)oc * HW + hw0;
        #pragma unroll
        for (int mm = 0; mm < 4; ++mm) {
            int pb2 = mm * 16 + (lane >> 4) * 4;
            #pragma unroll
            for (int r = 0; r < 4; ++r) {
                float yv = (acc[mm][nn][r] - mn) * sc + bt;
                float s = yv * __builtin_amdgcn_rcpf(1.f + __expf(-yv));
                orow[pb2 + r] = xr[pb2 + r] + s;
            }
        }
    }
}

extern "C" void kernel_launch(void* const* d_in, const int* in_sizes, int n_in,
                              void* d_out, int out_size, void* d_ws, size_t ws_size,
                              hipStream_t stream) {
    const float* x        = (const float*)d_in[0];
    const float* offset_w = (const float*)d_in[1];
    const float* offset_b = (const float*)d_in[2];
    const float* dcn_w    = (const float*)d_in[3];
    const float* gamma    = (const float*)d_in[4];
    const float* beta     = (const float*)d_in[5];
    const float* mean     = (const float*)d_in[6];
    const float* var      = (const float*)d_in[7];
    float* out = (float*)d_out;

    _Float16* xt   = (_Float16*)d_ws;                    // 13,107,200 B
    _Float16* wpk4 = xt + (size_t)NPIX * CH;             //  1,179,648 B
    _Float16* wopf = wpk4 + (size_t)NIV * 16384;         //    147,456 B
    float*    off4 = (float*)(wopf + (size_t)NCHUNK * 1024);  // 7,372,800 B

    k_transpose_x<<<dim3(HW / 32, CH / 32, BATCH), dim3(32, 8), 0, stream>>>(x, xt);
    k_pack_all<<<(NIV * 16384 + NCHUNK * 1024 + 255) / 256, 256, 0, stream>>>(dcn_w, offset_w, wpk4, wopf);
    k_offset<<<dim3(NBLK, 4), 256, 0, stream>>>(xt, wopf, off4);
    k_main<<<NBLK, 512, 0, stream>>>(x, xt, wpk4, off4, offset_b,
                                     gamma, beta, mean, var, out);
}